// Round 6
// baseline (3322.134 us; speedup 1.0000x reference)
//
#include <hip/hip_runtime.h>

#define NN 128
#define CCH 16
#define BB 4
#define HID 128
#define DOUT 128

typedef float v2f __attribute__((ext_vector_type(2)));

// ===========================================================================
// REAL kernels (round-5, correct): xpose_diag + fused_rey -> d_out
// ===========================================================================
__global__ __launch_bounds__(512) void xpose_diag(
    const float* __restrict__ x, float* __restrict__ xT, float* __restrict__ xd)
{
    __shared__ float tile[32][NN + 1];
    const int t  = threadIdx.x;
    const int bid = blockIdx.x;
    const int st = bid & 3;
    const int c  = (bid >> 2) & 15;
    const int b  = bid >> 6;
    const int q0 = st * 32;
    const float* xm = x + ((size_t)(b * CCH + c) << 14);

    #pragma unroll
    for (int pass = 0; pass < 2; ++pass) {
        const int i = (t >> 5) + pass * 16;
        const int m = (t & 31) * 4;
        const float4 v = *reinterpret_cast<const float4*>(&xm[(q0 + i) * NN + m]);
        tile[i][m] = v.x; tile[i][m+1] = v.y; tile[i][m+2] = v.z; tile[i][m+3] = v.w;
    }
    __syncthreads();
    if (t < 32) xd[(b * CCH + c) * NN + q0 + t] = tile[t][q0 + t];
    float* xTm = xT + ((size_t)(b * CCH + c) << 14);
    const int p = t >> 2;
    #pragma unroll
    for (int g = 0; g < 2; ++g) {
        const int qq = (t & 3) * 8 + g * 4;
        float4 v;
        v.x = tile[qq+0][p]; v.y = tile[qq+1][p]; v.z = tile[qq+2][p]; v.w = tile[qq+3][p];
        *reinterpret_cast<float4*>(&xTm[p * NN + q0 + qq]) = v;
    }
}

__global__ __launch_bounds__(512, 2) void fused_rey(
    const float* __restrict__ x, const float* __restrict__ xT,
    const float* __restrict__ xd,
    const float* __restrict__ W1, const float* __restrict__ b1,
    const float* __restrict__ W2, const float* __restrict__ b2,
    const float* __restrict__ Wc, const float* __restrict__ bc,
    float* __restrict__ y)
{
    __shared__ float s_out[CCH][NN];
    __shared__ float s_part[8][4];

    const int t   = threadIdx.x;
    const int bid = blockIdx.x;
    const int p   = bid & 127;
    const int b   = bid >> 7;
    const int q   = t & 127;
    const int cq  = t >> 7;
    const int wv  = t >> 6;
    const float bb0 = b2[0], bb1 = b2[1];

    v2f x_pp2[2], x_pq2[2], x_qp2[2], x_qq2[2];
    #pragma unroll
    for (int g = 0; g < 2; ++g)
        #pragma unroll
        for (int e = 0; e < 2; ++e) {
            const int c = cq + 4 * (2 * g + e);
            const size_t mbase = (size_t)(b * CCH + c) << 14;
            x_pq2[g][e] = x [mbase + p * NN + q];
            x_qp2[g][e] = xT[mbase + p * NN + q];
            x_qq2[g][e] = xd[(b * CCH + c) * NN + q];
            x_pp2[g][e] = xd[(b * CCH + c) * NN + p];
        }

    v2f h0_2[2], h1_2[2];
    const v2f z2 = { 0.f, 0.f };
    #pragma unroll
    for (int g = 0; g < 2; ++g) { h0_2[g] = (v2f){bb0, bb0}; h1_2[g] = (v2f){bb1, bb1}; }

    #pragma unroll 4
    for (int k = 0; k < HID; ++k) {
        const float4 w  = reinterpret_cast<const float4*>(W1)[k];
        const float b1k = b1[k];
        const v2f wx = {w.x,w.x}, wy = {w.y,w.y}, wz = {w.z,w.z}, ww = {w.w,w.w};
        const v2f bk = {b1k,b1k};
        const v2f w20 = {W2[k],W2[k]};
        const v2f w21 = {W2[HID+k],W2[HID+k]};
        #pragma unroll
        for (int g = 0; g < 2; ++g) {
            v2f hd = __builtin_elementwise_fma(wx, x_pp2[g], bk);
            hd = __builtin_elementwise_fma(wy, x_pq2[g], hd);
            hd = __builtin_elementwise_fma(wz, x_qp2[g], hd);
            hd = __builtin_elementwise_fma(ww, x_qq2[g], hd);
            hd = __builtin_elementwise_max(hd, z2);
            h0_2[g] = __builtin_elementwise_fma(w20, hd, h0_2[g]);
            h1_2[g] = __builtin_elementwise_fma(w21, hd, h1_2[g]);
        }
    }

    float h0s[4];
    #pragma unroll
    for (int g = 0; g < 2; ++g)
        #pragma unroll
        for (int e = 0; e < 2; ++e) {
            const int j = 2 * g + e;
            const int c = cq + 4 * j;
            s_out[c][q] = h1_2[g][e];
            h0s[j] = (q == p) ? 0.f : h0_2[g][e];
        }

    #pragma unroll
    for (int j = 0; j < 4; ++j) {
        float v = h0s[j];
        for (int off = 32; off > 0; off >>= 1)
            v += __shfl_down(v, off, 64);
        if ((t & 63) == 0) s_part[wv][j] = v;
    }
    __syncthreads();
    if (t < 16) {
        const int cq2 = t >> 2, j2 = t & 3;
        const int c2 = cq2 + 4 * j2;
        s_out[c2][p] = (s_part[2*cq2][j2] + s_part[2*cq2+1][j2]) * (1.0f / (NN - 1));
    }
    __syncthreads();

    const int lane = t & 63;
    const int m0 = lane * 2;
    v2f r[CCH];
    #pragma unroll
    for (int c = 0; c < CCH; ++c)
        r[c] = *reinterpret_cast<const v2f*>(&s_out[c][m0]);

    #pragma unroll
    for (int dd = 0; dd < 16; ++dd) {
        const int d = wv * 16 + dd;
        const float bcv = bc[d];
        v2f acc = { bcv, bcv };
        #pragma unroll
        for (int c = 0; c < CCH; ++c) {
            const float wcf = Wc[d * CCH + c];
            const v2f wcv = { wcf, wcf };
            acc = __builtin_elementwise_fma(wcv, r[c], acc);
        }
        acc = __builtin_elementwise_max(acc, z2);
        float* yp = y + ((((size_t)(b * DOUT + d)) * NN + p) * NN + m0);
        *reinterpret_cast<v2f*>(yp) = acc;
    }
}

// ===========================================================================
// PROBE 1: phase-1 k-loop, weights from MEMORY (round-5 path). REP=4.
// ===========================================================================
#define REP_MEMW 4
__global__ __launch_bounds__(512, 2) void probe_p1_memw(
    const float* __restrict__ x, const float* __restrict__ xT,
    const float* __restrict__ xd,
    const float* __restrict__ W1, const float* __restrict__ b1,
    const float* __restrict__ W2, const float* __restrict__ b2,
    float* __restrict__ wsout)
{
    const int t   = threadIdx.x;
    const int bid = blockIdx.x;
    const int p   = bid & 127;
    const int b   = bid >> 7;
    const int q   = t & 127;
    const int cq  = t >> 7;
    const float bb0 = b2[0], bb1 = b2[1];
    const v2f z2 = {0.f, 0.f}, eps2 = {1e-7f, 1e-7f};

    v2f x_pp2[2], x_pq2[2], x_qp2[2], x_qq2[2];
    #pragma unroll
    for (int g = 0; g < 2; ++g)
        #pragma unroll
        for (int e = 0; e < 2; ++e) {
            const int c = cq + 4 * (2 * g + e);
            const size_t mbase = (size_t)(b * CCH + c) << 14;
            x_pq2[g][e] = x [mbase + p * NN + q];
            x_qp2[g][e] = xT[mbase + p * NN + q];
            x_qq2[g][e] = xd[(b * CCH + c) * NN + q];
            x_pp2[g][e] = xd[(b * CCH + c) * NN + p];
        }

    v2f acc = z2;
    #pragma unroll 1
    for (int r = 0; r < REP_MEMW; ++r) {
        x_pq2[0] += eps2; x_pq2[1] += eps2;   // defeat cross-rep CSE
        v2f h0_2[2], h1_2[2];
        const float bi = bb0 + 1e-6f * (float)r;
        #pragma unroll
        for (int g = 0; g < 2; ++g) { h0_2[g] = (v2f){bi, bi}; h1_2[g] = (v2f){bb1, bb1}; }
        #pragma unroll 4
        for (int k = 0; k < HID; ++k) {
            const float4 w  = reinterpret_cast<const float4*>(W1)[k];
            const float b1k = b1[k];
            const v2f wx = {w.x,w.x}, wy = {w.y,w.y}, wz = {w.z,w.z}, ww = {w.w,w.w};
            const v2f bk = {b1k,b1k};
            const v2f w20 = {W2[k],W2[k]};
            const v2f w21 = {W2[HID+k],W2[HID+k]};
            #pragma unroll
            for (int g = 0; g < 2; ++g) {
                v2f hd = __builtin_elementwise_fma(wx, x_pp2[g], bk);
                hd = __builtin_elementwise_fma(wy, x_pq2[g], hd);
                hd = __builtin_elementwise_fma(wz, x_qp2[g], hd);
                hd = __builtin_elementwise_fma(ww, x_qq2[g], hd);
                hd = __builtin_elementwise_max(hd, z2);
                h0_2[g] = __builtin_elementwise_fma(w20, hd, h0_2[g]);
                h1_2[g] = __builtin_elementwise_fma(w21, hd, h1_2[g]);
            }
        }
        acc += h0_2[0] + h0_2[1] + h1_2[0] + h1_2[1];
    }
    wsout[bid * 512 + t] = acc[0] + acc[1];
}

// ===========================================================================
// PROBE 2: same loop, SYNTHETIC weights (no memory in loop). REP=6.
// ===========================================================================
#define REP_SYNW 6
__global__ __launch_bounds__(512, 2) void probe_p1_synw(
    const float* __restrict__ x, const float* __restrict__ xT,
    const float* __restrict__ xd,
    const float* __restrict__ b2, float* __restrict__ wsout)
{
    const int t   = threadIdx.x;
    const int bid = blockIdx.x;
    const int p   = bid & 127;
    const int b   = bid >> 7;
    const int q   = t & 127;
    const int cq  = t >> 7;
    const float bb0 = b2[0], bb1 = b2[1];
    const v2f z2 = {0.f, 0.f}, eps2 = {1e-7f, 1e-7f};

    v2f x_pp2[2], x_pq2[2], x_qp2[2], x_qq2[2];
    #pragma unroll
    for (int g = 0; g < 2; ++g)
        #pragma unroll
        for (int e = 0; e < 2; ++e) {
            const int c = cq + 4 * (2 * g + e);
            const size_t mbase = (size_t)(b * CCH + c) << 14;
            x_pq2[g][e] = x [mbase + p * NN + q];
            x_qp2[g][e] = xT[mbase + p * NN + q];
            x_qq2[g][e] = xd[(b * CCH + c) * NN + q];
            x_pp2[g][e] = xd[(b * CCH + c) * NN + p];
        }

    v2f acc = z2;
    #pragma unroll 1
    for (int r = 0; r < REP_SYNW; ++r) {
        x_pq2[0] += eps2; x_pq2[1] += eps2;
        v2f h0_2[2], h1_2[2];
        const float bi = bb0 + 1e-6f * (float)r;
        #pragma unroll
        for (int g = 0; g < 2; ++g) { h0_2[g] = (v2f){bi, bi}; h1_2[g] = (v2f){bb1, bb1}; }
        #pragma unroll 4
        for (int k = 0; k < HID; ++k) {
            const float fk = (float)k;                 // synthesized weights
            const v2f wx = {fk*1e-3f, fk*1e-3f};
            const v2f wy = {fk*-2e-3f, fk*-2e-3f};
            const v2f wz = {fk*1.5e-3f, fk*1.5e-3f};
            const v2f ww = {fk*0.5e-3f, fk*0.5e-3f};
            const v2f bk = {fk*1e-4f + 0.01f, fk*1e-4f + 0.01f};
            const v2f w20 = {fk*3e-4f + 0.05f, fk*3e-4f + 0.05f};
            const v2f w21 = {fk*-2e-4f - 0.07f, fk*-2e-4f - 0.07f};
            #pragma unroll
            for (int g = 0; g < 2; ++g) {
                v2f hd = __builtin_elementwise_fma(wx, x_pp2[g], bk);
                hd = __builtin_elementwise_fma(wy, x_pq2[g], hd);
                hd = __builtin_elementwise_fma(wz, x_qp2[g], hd);
                hd = __builtin_elementwise_fma(ww, x_qq2[g], hd);
                hd = __builtin_elementwise_max(hd, z2);
                h0_2[g] = __builtin_elementwise_fma(w20, hd, h0_2[g]);
                h1_2[g] = __builtin_elementwise_fma(w21, hd, h1_2[g]);
            }
        }
        acc += h0_2[0] + h0_2[1] + h1_2[0] + h1_2[1];
    }
    wsout[bid * 512 + t] = acc[0] + acc[1];
}

// ===========================================================================
// PROBE 3: split-k across waves, weights pinned in VGPRs (shfl). REP=16,
// quarter work per rep -> total work == probe1's 4 units.
// ===========================================================================
#define REP_REGW 16
__global__ __launch_bounds__(512, 2) void probe_p1_regw(
    const float* __restrict__ x, const float* __restrict__ xT,
    const float* __restrict__ xd,
    const float* __restrict__ W1, const float* __restrict__ b1,
    const float* __restrict__ W2, const float* __restrict__ b2,
    float* __restrict__ wsout)
{
    const int t    = threadIdx.x;
    const int bid  = blockIdx.x;
    const int p    = bid & 127;
    const int b    = bid >> 7;
    const int lane = t & 63;
    const int wv   = t >> 6;
    const int kb   = wv * 16;
    const float bb0 = b2[0], bb1 = b2[1];
    const v2f z2 = {0.f, 0.f}, eps2 = {1e-7f, 1e-7f};

    // pin weights for k = kb..kb+15 into VGPRs (shfl forces divergent copy)
    float w1x[16], w1y[16], w1z[16], w1w[16], b1v[16], w20v[16], w21v[16];
    #pragma unroll
    for (int kk = 0; kk < 16; ++kk) {
        const float4 wrow = reinterpret_cast<const float4*>(W1)[kb + kk];
        w1x[kk]  = __shfl(wrow.x, 0);
        w1y[kk]  = __shfl(wrow.y, 0);
        w1z[kk]  = __shfl(wrow.z, 0);
        w1w[kk]  = __shfl(wrow.w, 0);
        b1v[kk]  = __shfl(b1[kb + kk], 0);
        w20v[kk] = __shfl(W2[kb + kk], 0);
        w21v[kk] = __shfl(W2[HID + kb + kk], 0);
    }

    // two q's per thread, 4 channels, packed over the q-pair
    const int q1 = lane, q2 = lane + 64;
    v2f xpq[4], xqp[4], xqq[4]; float xpp[4];
    #pragma unroll
    for (int c = 0; c < 4; ++c) {
        const size_t mbase = (size_t)(b * CCH + c) << 14;
        xpq[c] = (v2f){ x [mbase + p * NN + q1], x [mbase + p * NN + q2] };
        xqp[c] = (v2f){ xT[mbase + p * NN + q1], xT[mbase + p * NN + q2] };
        xqq[c] = (v2f){ xd[(b * CCH + c) * NN + q1], xd[(b * CCH + c) * NN + q2] };
        xpp[c] = xd[(b * CCH + c) * NN + p];
    }

    v2f acc = z2;
    #pragma unroll 1
    for (int r = 0; r < REP_REGW; ++r) {
        #pragma unroll
        for (int c = 0; c < 4; ++c) xpq[c] += eps2;
        v2f h0[4], h1[4];
        const float bi = bb0 + 1e-6f * (float)r;
        #pragma unroll
        for (int c = 0; c < 4; ++c) { h0[c] = (v2f){bi, bi}; h1[c] = (v2f){bb1, bb1}; }
        #pragma unroll
        for (int kk = 0; kk < 16; ++kk) {
            const v2f wx = {w1x[kk], w1x[kk]}, wy = {w1y[kk], w1y[kk]};
            const v2f wz = {w1z[kk], w1z[kk]}, ww = {w1w[kk], w1w[kk]};
            const v2f bk = {b1v[kk], b1v[kk]};
            const v2f w20 = {w20v[kk], w20v[kk]}, w21 = {w21v[kk], w21v[kk]};
            #pragma unroll
            for (int c = 0; c < 4; ++c) {
                const v2f xp = {xpp[c], xpp[c]};
                v2f hd = __builtin_elementwise_fma(wx, xp, bk);
                hd = __builtin_elementwise_fma(wy, xpq[c], hd);
                hd = __builtin_elementwise_fma(wz, xqp[c], hd);
                hd = __builtin_elementwise_fma(ww, xqq[c], hd);
                hd = __builtin_elementwise_max(hd, z2);
                h0[c] = __builtin_elementwise_fma(w20, hd, h0[c]);
                h1[c] = __builtin_elementwise_fma(w21, hd, h1[c]);
            }
        }
        #pragma unroll
        for (int c = 0; c < 4; ++c) acc += h0[c] + h1[c];
    }
    wsout[bid * 512 + t] = acc[0] + acc[1];
}

// ===========================================================================
// PROBE 4: phase-2 compute mix (scalar Wc loads + pk fma), REP=24.
// ===========================================================================
#define REP_P2 24
__global__ __launch_bounds__(512, 2) void probe_p2(
    const float* __restrict__ Wc, const float* __restrict__ bc,
    float* __restrict__ wsout)
{
    __shared__ float s_out[CCH][NN];
    const int t = threadIdx.x;
    const int bid = blockIdx.x;
    #pragma unroll
    for (int i = 0; i < 4; ++i) {
        const int idx = t * 4 + i;
        reinterpret_cast<float*>(s_out)[idx] = (float)(idx & 255) * 0.01f;
    }
    __syncthreads();

    const int lane = t & 63, wv = t >> 6;
    const int m0 = lane * 2;
    const v2f z2 = {0.f, 0.f};
    v2f r[CCH];
    #pragma unroll
    for (int c = 0; c < CCH; ++c)
        r[c] = *reinterpret_cast<const v2f*>(&s_out[c][m0]);

    v2f accsum[16];
    #pragma unroll
    for (int dd = 0; dd < 16; ++dd) accsum[dd] = z2;

    #pragma unroll 1
    for (int rep = 0; rep < REP_P2; ++rep) {
        #pragma unroll
        for (int dd = 0; dd < 16; ++dd) {
            const int d = wv * 16 + dd;
            const float bcv = bc[d] + 1e-6f * (float)rep;
            v2f acc = { bcv, bcv };
            #pragma unroll
            for (int c = 0; c < CCH; ++c) {
                const float wcf = Wc[d * CCH + c];
                const v2f wcv = { wcf, wcf };
                acc = __builtin_elementwise_fma(wcv, r[c], acc);
            }
            acc = __builtin_elementwise_max(acc, z2);
            accsum[dd] += acc;
        }
    }
    v2f tot = z2;
    #pragma unroll
    for (int dd = 0; dd < 16; ++dd) tot += accsum[dd];
    wsout[bid * 512 + t] = tot[0] + tot[1];
}

extern "C" void kernel_launch(void* const* d_in, const int* in_sizes, int n_in,
                              void* d_out, int out_size, void* d_ws, size_t ws_size,
                              hipStream_t stream) {
    const float* x  = (const float*)d_in[0];
    const float* W1 = (const float*)d_in[1];
    const float* b1 = (const float*)d_in[2];
    const float* W2 = (const float*)d_in[3];
    const float* b2 = (const float*)d_in[4];
    const float* Wc = (const float*)d_in[5];
    const float* bc = (const float*)d_in[6];
    float* y  = (float*)d_out;

    float* xT = (float*)d_ws;                                 // 4 MiB
    float* xd = (float*)d_ws + (size_t)BB * CCH * NN * NN;    // +32 KiB
    float* po = (float*)d_ws + (size_t)2097152;               // probe outputs @8 MiB

    // real pipeline (correct output)
    xpose_diag<<<dim3(BB * CCH * 4), 512, 0, stream>>>(x, xT, xd);
    fused_rey<<<dim3(BB * NN), 512, 0, stream>>>(x, xT, xd, W1, b1, W2, b2, Wc, bc, y);

    // ablation probes (write to ws only)
    probe_p1_memw<<<dim3(BB * NN), 512, 0, stream>>>(x, xT, xd, W1, b1, W2, b2, po);
    probe_p1_synw<<<dim3(BB * NN), 512, 0, stream>>>(x, xT, xd, b2, po + 262144);
    probe_p1_regw<<<dim3(BB * NN), 512, 0, stream>>>(x, xT, xd, W1, b1, W2, b2, po + 524288);
    probe_p2<<<dim3(BB * NN), 512, 0, stream>>>(Wc, bc, po + 786432);
}

// Round 7
// 194.967 us; speedup vs baseline: 17.0395x; 17.0395x over previous
//
#include <hip/hip_runtime.h>

#define NN 128
#define CCH 16
#define BB 4
#define HID 128
#define DOUT 128

typedef float v2f __attribute__((ext_vector_type(2)));

// ws layout (float offsets). ws >= 262 MB per harness fills.
#define XT_OFF   0u            // 1,048,576 floats (4 MiB)
#define XD_OFF   1048576u      // 8,192 floats
#define WPK_OFF  1064960u      // 1,024 floats ([128][8] packed weights)
#define H1_OFF   2097152u      // 1,048,576 floats
#define DG_OFF   4194304u      // 16,384 floats (diag partials [b][c][p][qh])
#define PR_OFF   8388608u      // probe junk

// ---------------------------------------------------------------------------
// prep: pack weights into [k][8] = {w0,w1,w2,w3,b1,w20,w21,0}
// ---------------------------------------------------------------------------
__global__ void prep_weights(const float* __restrict__ W1, const float* __restrict__ b1,
                             const float* __restrict__ W2, float* __restrict__ wpk)
{
    const int k = threadIdx.x;
    const float4 w = reinterpret_cast<const float4*>(W1)[k];
    wpk[k * 8 + 0] = w.x;  wpk[k * 8 + 1] = w.y;
    wpk[k * 8 + 2] = w.z;  wpk[k * 8 + 3] = w.w;
    wpk[k * 8 + 4] = b1[k];
    wpk[k * 8 + 5] = W2[k];
    wpk[k * 8 + 6] = W2[HID + k];
    wpk[k * 8 + 7] = 0.f;
}

// ---------------------------------------------------------------------------
// xpose: per (b,c,32-row stripe) transpose -> xT, diagonal -> xd (validated)
// ---------------------------------------------------------------------------
__global__ __launch_bounds__(512) void xpose_diag(
    const float* __restrict__ x, float* __restrict__ xT, float* __restrict__ xd)
{
    __shared__ float tile[32][NN + 1];
    const int t  = threadIdx.x;
    const int bid = blockIdx.x;
    const int st = bid & 3;
    const int c  = (bid >> 2) & 15;
    const int b  = bid >> 6;
    const int q0 = st * 32;
    const float* xm = x + ((size_t)(b * CCH + c) << 14);

    #pragma unroll
    for (int pass = 0; pass < 2; ++pass) {
        const int i = (t >> 5) + pass * 16;
        const int m = (t & 31) * 4;
        const float4 v = *reinterpret_cast<const float4*>(&xm[(q0 + i) * NN + m]);
        tile[i][m] = v.x; tile[i][m+1] = v.y; tile[i][m+2] = v.z; tile[i][m+3] = v.w;
    }
    __syncthreads();
    if (t < 32) xd[(b * CCH + c) * NN + q0 + t] = tile[t][q0 + t];
    float* xTm = xT + ((size_t)(b * CCH + c) << 14);
    const int p = t >> 2;
    #pragma unroll
    for (int g = 0; g < 2; ++g) {
        const int qq = (t & 3) * 8 + g * 4;
        float4 v;
        v.x = tile[qq+0][p]; v.y = tile[qq+1][p]; v.z = tile[qq+2][p]; v.w = tile[qq+3][p];
        *reinterpret_cast<float4*>(&xTm[p * NN + q0 + qq]) = v;
    }
}

// ---------------------------------------------------------------------------
// k1: phase 1. Block = (b, p, q-half). 256 threads, 4 waves, NO LDS/barriers.
// Wave = (channel-group cg = t>>6); lane covers q = qh*64 + (t&63).
// Each thread: 4 channels (2 v2f), 1 q. h1 -> ws, per-wave diag partial -> ws.
// ---------------------------------------------------------------------------
__global__ void k1_phase1(
    const float* __restrict__ x, const float* __restrict__ xT,
    const float* __restrict__ xd, const float* __restrict__ wpk,
    const float* __restrict__ b2,
    float* __restrict__ h1ws, float* __restrict__ dgws)
{
    const int t   = threadIdx.x;
    const int bid = blockIdx.x;
    const int qh  = bid & 1;
    const int p   = (bid >> 1) & 127;
    const int b   = bid >> 8;
    const int q   = qh * 64 + (t & 63);
    const int cg  = t >> 6;               // 0..3 (wave-uniform)

    const float bb0 = b2[0], bb1 = b2[1];
    const v2f z2 = { 0.f, 0.f };

    // x values for channels c = cg*4 + e, e=0..3, packed (e0,e1),(e2,e3)
    v2f xpq2[2], xqp2[2], xqq2[2], xpp2[2];
    #pragma unroll
    for (int g = 0; g < 2; ++g)
        #pragma unroll
        for (int e = 0; e < 2; ++e) {
            const int c = cg * 4 + 2 * g + e;
            const size_t mbase = (size_t)(b * CCH + c) << 14;
            xpq2[g][e] = x [mbase + p * NN + q];
            xqp2[g][e] = xT[mbase + p * NN + q];
            xqq2[g][e] = xd[(b * CCH + c) * NN + q];
            xpp2[g][e] = xd[(b * CCH + c) * NN + p];   // wave-uniform
        }

    v2f h0_2[2] = { { bb0, bb0 }, { bb0, bb0 } };
    v2f h1_2[2] = { { bb1, bb1 }, { bb1, bb1 } };

    const float4* wp4 = reinterpret_cast<const float4*>(wpk);
    #pragma unroll 4
    for (int k = 0; k < HID; ++k) {
        const float4 wA = wp4[2 * k];       // w0 w1 w2 w3   (uniform -> s_load)
        const float4 wB = wp4[2 * k + 1];   // b1 w20 w21 -
        const v2f wx = { wA.x, wA.x }, wy = { wA.y, wA.y };
        const v2f wz = { wA.z, wA.z }, ww = { wA.w, wA.w };
        const v2f bk = { wB.x, wB.x };
        const v2f w20 = { wB.y, wB.y }, w21 = { wB.z, wB.z };
        #pragma unroll
        for (int g = 0; g < 2; ++g) {
            v2f hd = __builtin_elementwise_fma(wx, xpp2[g], bk);
            hd = __builtin_elementwise_fma(wy, xpq2[g], hd);
            hd = __builtin_elementwise_fma(wz, xqp2[g], hd);
            hd = __builtin_elementwise_fma(ww, xqq2[g], hd);
            hd = __builtin_elementwise_max(hd, z2);
            h0_2[g] = __builtin_elementwise_fma(w20, hd, h0_2[g]);
            h1_2[g] = __builtin_elementwise_fma(w21, hd, h1_2[g]);
        }
    }

    // h1 -> ws (q==p slot later overwritten by k2); diag partial per wave
    float h0s[4];
    #pragma unroll
    for (int g = 0; g < 2; ++g)
        #pragma unroll
        for (int e = 0; e < 2; ++e) {
            const int c = cg * 4 + 2 * g + e;
            h1ws[((size_t)(b * CCH + c) * NN + p) * NN + q] = h1_2[g][e];
            h0s[2 * g + e] = (q == p) ? 0.f : h0_2[g][e];
        }

    #pragma unroll
    for (int e = 0; e < 4; ++e) {
        float v = h0s[e];
        for (int off = 32; off > 0; off >>= 1)
            v += __shfl_down(v, off, 64);
        if ((t & 63) == 0) {
            const int c = cg * 4 + e;
            dgws[((b * CCH + c) * NN + p) * 2 + qh] = v;
        }
    }
}

// ---------------------------------------------------------------------------
// k2: phase 2. Block = (b, p). 256 threads, 4 waves. Stage h1-row + diag fix
// in LDS, then channel mix 16->128 + ReLU, streamed to y.
// ---------------------------------------------------------------------------
__global__ void k2_phase2(
    const float* __restrict__ h1ws, const float* __restrict__ dgws,
    const float* __restrict__ Wc, const float* __restrict__ bc,
    float* __restrict__ y)
{
    __shared__ float s_out[CCH][NN];   // 8 KB
    const int t   = threadIdx.x;
    const int bid = blockIdx.x;
    const int p   = bid & 127;
    const int b   = bid >> 7;

    #pragma unroll
    for (int i = 0; i < 8; ++i) {
        const int idx = t + i * 256;
        const int c = idx >> 7, m = idx & 127;
        s_out[c][m] = h1ws[((size_t)(b * CCH + c) * NN + p) * NN + m];
    }
    __syncthreads();
    if (t < CCH) {
        const int c = t;
        const float d0 = dgws[((b * CCH + c) * NN + p) * 2 + 0];
        const float d1 = dgws[((b * CCH + c) * NN + p) * 2 + 1];
        s_out[c][p] = (d0 + d1) * (1.0f / (NN - 1));
    }
    __syncthreads();

    const int lane = t & 63;
    const int wv   = t >> 6;           // 0..3 -> 32 d's each
    const int m0   = lane * 2;
    const v2f z2 = { 0.f, 0.f };
    v2f r[CCH];
    #pragma unroll
    for (int c = 0; c < CCH; ++c)
        r[c] = *reinterpret_cast<const v2f*>(&s_out[c][m0]);

    #pragma unroll 4
    for (int dd = 0; dd < 32; ++dd) {
        const int d = wv * 32 + dd;            // wave-uniform
        const float bcv = bc[d];
        v2f acc = { bcv, bcv };
        #pragma unroll
        for (int c = 0; c < CCH; ++c) {
            const float wcf = Wc[d * CCH + c]; // uniform -> scalar
            const v2f wcv = { wcf, wcf };
            acc = __builtin_elementwise_fma(wcv, r[c], acc);
        }
        acc = __builtin_elementwise_max(acc, z2);
        float* yp = y + ((((size_t)(b * DOUT + d)) * NN + p) * NN + m0);
        *reinterpret_cast<v2f*>(yp) = acc;
    }
}

// ---------------------------------------------------------------------------
// PROBE: round-5 fused phase-1 loop verbatim (same shape/bounds), REP=8.
// Steady-state counters for the suspect loop. Output to ws only.
// ---------------------------------------------------------------------------
#define PREP 8
__global__ __launch_bounds__(512, 2) void probe_p1(
    const float* __restrict__ x, const float* __restrict__ xT,
    const float* __restrict__ xd,
    const float* __restrict__ W1, const float* __restrict__ b1,
    const float* __restrict__ W2, const float* __restrict__ b2,
    float* __restrict__ wsout)
{
    const int t   = threadIdx.x;
    const int bid = blockIdx.x;
    const int p   = bid & 127;
    const int b   = bid >> 7;
    const int q   = t & 127;
    const int cq  = t >> 7;
    const float bb0 = b2[0], bb1 = b2[1];
    const v2f z2 = {0.f, 0.f}, eps2 = {1e-7f, 1e-7f};

    v2f x_pp2[2], x_pq2[2], x_qp2[2], x_qq2[2];
    #pragma unroll
    for (int g = 0; g < 2; ++g)
        #pragma unroll
        for (int e = 0; e < 2; ++e) {
            const int c = cq + 4 * (2 * g + e);
            const size_t mbase = (size_t)(b * CCH + c) << 14;
            x_pq2[g][e] = x [mbase + p * NN + q];
            x_qp2[g][e] = xT[mbase + p * NN + q];
            x_qq2[g][e] = xd[(b * CCH + c) * NN + q];
            x_pp2[g][e] = xd[(b * CCH + c) * NN + p];
        }

    v2f acc = z2;
    #pragma unroll 1
    for (int r = 0; r < PREP; ++r) {
        x_pq2[0] += eps2; x_pq2[1] += eps2;   // defeat cross-rep CSE
        v2f h0_2[2], h1_2[2];
        const float bi = bb0 + 1e-6f * (float)r;
        #pragma unroll
        for (int g = 0; g < 2; ++g) { h0_2[g] = (v2f){bi, bi}; h1_2[g] = (v2f){bb1, bb1}; }
        #pragma unroll 4
        for (int k = 0; k < HID; ++k) {
            const float4 w  = reinterpret_cast<const float4*>(W1)[k];
            const float b1k = b1[k];
            const v2f wx = {w.x,w.x}, wy = {w.y,w.y}, wz = {w.z,w.z}, ww = {w.w,w.w};
            const v2f bk = {b1k,b1k};
            const v2f w20 = {W2[k],W2[k]};
            const v2f w21 = {W2[HID+k],W2[HID+k]};
            #pragma unroll
            for (int g = 0; g < 2; ++g) {
                v2f hd = __builtin_elementwise_fma(wx, x_pp2[g], bk);
                hd = __builtin_elementwise_fma(wy, x_pq2[g], hd);
                hd = __builtin_elementwise_fma(wz, x_qp2[g], hd);
                hd = __builtin_elementwise_fma(ww, x_qq2[g], hd);
                hd = __builtin_elementwise_max(hd, z2);
                h0_2[g] = __builtin_elementwise_fma(w20, hd, h0_2[g]);
                h1_2[g] = __builtin_elementwise_fma(w21, hd, h1_2[g]);
            }
        }
        acc += h0_2[0] + h0_2[1] + h1_2[0] + h1_2[1];
    }
    wsout[bid * 512 + t] = acc[0] + acc[1];
}

extern "C" void kernel_launch(void* const* d_in, const int* in_sizes, int n_in,
                              void* d_out, int out_size, void* d_ws, size_t ws_size,
                              hipStream_t stream) {
    const float* x  = (const float*)d_in[0];
    const float* W1 = (const float*)d_in[1];
    const float* b1 = (const float*)d_in[2];
    const float* W2 = (const float*)d_in[3];
    const float* b2 = (const float*)d_in[4];
    const float* Wc = (const float*)d_in[5];
    const float* bc = (const float*)d_in[6];
    float* y  = (float*)d_out;
    float* ws = (float*)d_ws;

    float* xT  = ws + XT_OFF;
    float* xd  = ws + XD_OFF;
    float* wpk = ws + WPK_OFF;
    float* h1w = ws + H1_OFF;
    float* dgw = ws + DG_OFF;
    float* prb = ws + PR_OFF;

    prep_weights<<<dim3(1), 128, 0, stream>>>(W1, b1, W2, wpk);
    xpose_diag<<<dim3(BB * CCH * 4), 512, 0, stream>>>(x, xT, xd);
    k1_phase1<<<dim3(BB * NN * 2), 256, 0, stream>>>(x, xT, xd, wpk, b2, h1w, dgw);
    k2_phase2<<<dim3(BB * NN), 256, 0, stream>>>(h1w, dgw, Wc, bc, y);

    // diagnostic probe (writes to ws only)
    probe_p1<<<dim3(BB * NN), 512, 0, stream>>>(x, xT, xd, W1, b1, W2, b2, prb);
}

// Round 8
// 43.231 us; speedup vs baseline: 76.8455x; 4.5098x over previous
//
#include <hip/hip_runtime.h>

#define NN 128
#define CCH 16
#define BB 4
#define HID 128
#define DOUT 128

// ws float offsets
#define XT_OFF  0u           // [b][c][128][128] transpose (4 MiB)
#define XD_OFF  1048576u     // [b][c][128] diagonals
#define WD_OFF  1056768u     // [128][8] packed MLP weights

// ---------------------------------------------------------------------------
// xpose_prep: per (b,c,32-row stripe): coalesced transpose -> xT, diag -> xd.
// Block 0 additionally packs MLP weights into wd[k][8] =
// {W1[k][0..3], b1[k], W2[0][k], W2[1][k], 0}.
// ---------------------------------------------------------------------------
__global__ __launch_bounds__(512) void xpose_prep(
    const float* __restrict__ x,
    const float* __restrict__ W1, const float* __restrict__ b1,
    const float* __restrict__ W2, float* __restrict__ ws)
{
    __shared__ float tile[32][NN + 1];
    const int t   = threadIdx.x;
    const int bid = blockIdx.x;
    const int st  = bid & 3;
    const int c   = (bid >> 2) & 15;
    const int b   = bid >> 6;
    const int q0  = st * 32;
    const float* xm = x + ((size_t)(b * CCH + c) << 14);
    float* xT = ws + XT_OFF;
    float* xd = ws + XD_OFF;

    if (bid == 0 && t < HID) {
        const float4 w = reinterpret_cast<const float4*>(W1)[t];
        float* wd = ws + WD_OFF + t * 8;
        wd[0] = w.x; wd[1] = w.y; wd[2] = w.z; wd[3] = w.w;
        wd[4] = b1[t]; wd[5] = W2[t]; wd[6] = W2[HID + t]; wd[7] = 0.f;
    }

    #pragma unroll
    for (int pass = 0; pass < 2; ++pass) {
        const int i = (t >> 5) + pass * 16;
        const int m = (t & 31) * 4;
        const float4 v = *reinterpret_cast<const float4*>(&xm[(q0 + i) * NN + m]);
        tile[i][m] = v.x; tile[i][m+1] = v.y; tile[i][m+2] = v.z; tile[i][m+3] = v.w;
    }
    __syncthreads();
    if (t < 32) xd[(b * CCH + c) * NN + q0 + t] = tile[t][q0 + t];
    float* xTm = xT + ((size_t)(b * CCH + c) << 14);
    const int p = t >> 2;
    #pragma unroll
    for (int g = 0; g < 2; ++g) {
        const int qq = (t & 3) * 8 + g * 4;
        float4 v;
        v.x = tile[qq+0][p]; v.y = tile[qq+1][p]; v.z = tile[qq+2][p]; v.w = tile[qq+3][p];
        *reinterpret_cast<float4*>(&xTm[p * NN + q0 + qq]) = v;
    }
}

// ---------------------------------------------------------------------------
// fused_rey: block = (b, row p), 512 threads = 8 waves.
// Phase 1: thread (c = t>>5, qg = t&31) handles 4 q's (q0 = qg*4) of channel
//   c. Per k: a = W1[k][0]*x_pp + b1[k] amortized over the 4 q's ->
//   6.5 VALU ops per hidden-unit-cell. Weights via uniform s_loads of the
//   packed wd[k][8]. No LDS in the hot loop.
// Diag: register mask + width-32 shuffle reduce (threads of one c are one
//   32-lane shuffle group).
// Phase 2: per wave 16 d's (wave-uniform -> scalar Wc/bc loads), lane covers
//   m pair; scalar fma (fp32 packed math has no throughput gain on CDNA4).
// ---------------------------------------------------------------------------
__global__ __launch_bounds__(512) void fused_rey(
    const float* __restrict__ x, const float* __restrict__ wsr,
    const float* __restrict__ b2,
    const float* __restrict__ Wc, const float* __restrict__ bc,
    float* __restrict__ y)
{
    __shared__ float s_out[CCH][NN];   // 8 KB

    const int t   = threadIdx.x;
    const int bid = blockIdx.x;
    const int p   = bid & 127;
    const int b   = bid >> 7;
    const int c   = t >> 5;            // 0..15
    const int qg  = t & 31;
    const int q0  = qg * 4;

    const float* xT = wsr + XT_OFF;
    const float* xd = wsr + XD_OFF;
    const float4* wd4 = reinterpret_cast<const float4*>(wsr + WD_OFF);

    const size_t mbase = (size_t)(b * CCH + c) << 14;
    const float4 vpq = *reinterpret_cast<const float4*>(&x [mbase + p * NN + q0]);
    const float4 vqp = *reinterpret_cast<const float4*>(&xT[mbase + p * NN + q0]);
    const float4 vqq = *reinterpret_cast<const float4*>(&xd[(b * CCH + c) * NN + q0]);
    const float  xpp = xd[(b * CCH + c) * NN + p];

    const float xpq[4] = { vpq.x, vpq.y, vpq.z, vpq.w };
    const float xqp[4] = { vqp.x, vqp.y, vqp.z, vqp.w };
    const float xqq[4] = { vqq.x, vqq.y, vqq.z, vqq.w };

    float h0[4] = { 0.f, 0.f, 0.f, 0.f };
    float h1[4] = { 0.f, 0.f, 0.f, 0.f };

    #pragma unroll 4
    for (int k = 0; k < HID; ++k) {
        const float4 wA = wd4[2 * k];        // w0 w1 w2 w3  (uniform -> s_load)
        const float4 wB = wd4[2 * k + 1];    // b1 w20 w21 -
        const float a = fmaf(wA.x, xpp, wB.x);   // q-invariant, amortized over 4 q
        #pragma unroll
        for (int j = 0; j < 4; ++j) {
            float hd = fmaf(wA.y, xpq[j], a);
            hd = fmaf(wA.z, xqp[j], hd);
            hd = fmaf(wA.w, xqq[j], hd);
            hd = fmaxf(hd, 0.f);
            h0[j] = fmaf(wB.y, hd, h0[j]);
            h1[j] = fmaf(wB.z, hd, h1[j]);
        }
    }

    const float bb0 = b2[0], bb1 = b2[1];

    // h1 (+b2[1]) -> LDS row c ((p,p) slot fixed after barrier)
    float4 o;
    o.x = h1[0] + bb1; o.y = h1[1] + bb1; o.z = h1[2] + bb1; o.w = h1[3] + bb1;
    *reinterpret_cast<float4*>(&s_out[c][q0]) = o;

    // diag partial: mask q==p, reduce across the 32 threads of this c
    float s = 0.f;
    #pragma unroll
    for (int j = 0; j < 4; ++j)
        s += (q0 + j == p) ? 0.f : h0[j];
    #pragma unroll
    for (int off = 16; off > 0; off >>= 1)
        s += __shfl_down(s, off, 32);

    __syncthreads();
    if (qg == 0) s_out[c][p] = s * (1.0f / (NN - 1)) + bb0;
    __syncthreads();

    // ---- phase 2: y[b,d,p,:] = relu(sum_c s_out[c]*Wc[d][c] + bc[d]) ----
    const int wv = t >> 6;             // 0..7 -> 16 d's each
    const int m0 = (t & 63) * 2;
    float rx[CCH], ry[CCH];
    #pragma unroll
    for (int cc = 0; cc < CCH; ++cc) {
        const float2 rv = *reinterpret_cast<const float2*>(&s_out[cc][m0]);
        rx[cc] = rv.x; ry[cc] = rv.y;
    }

    #pragma unroll 4
    for (int dd = 0; dd < 16; ++dd) {
        const int d = wv * 16 + dd;        // wave-uniform
        const float bcv = bc[d];           // scalar load
        float ax = bcv, ay = bcv;
        #pragma unroll
        for (int cc = 0; cc < CCH; ++cc) {
            const float wcf = Wc[d * CCH + cc];   // scalar load
            ax = fmaf(wcf, rx[cc], ax);
            ay = fmaf(wcf, ry[cc], ay);
        }
        float2 ov;
        ov.x = fmaxf(ax, 0.f);
        ov.y = fmaxf(ay, 0.f);
        *reinterpret_cast<float2*>(&y[(((size_t)(b * DOUT + d)) * NN + p) * NN + m0]) = ov;
    }
}

extern "C" void kernel_launch(void* const* d_in, const int* in_sizes, int n_in,
                              void* d_out, int out_size, void* d_ws, size_t ws_size,
                              hipStream_t stream) {
    const float* x  = (const float*)d_in[0];
    const float* W1 = (const float*)d_in[1];
    const float* b1 = (const float*)d_in[2];
    const float* W2 = (const float*)d_in[3];
    const float* b2 = (const float*)d_in[4];
    const float* Wc = (const float*)d_in[5];
    const float* bc = (const float*)d_in[6];
    float* y  = (float*)d_out;
    float* ws = (float*)d_ws;

    xpose_prep<<<dim3(BB * CCH * 4), 512, 0, stream>>>(x, W1, b1, W2, ws);
    fused_rey<<<dim3(BB * NN), 512, 0, stream>>>(x, ws, b2, Wc, bc, y);
}